// Round 4
// baseline (448.628 us; speedup 1.0000x reference)
//
#include <hip/hip_runtime.h>
#include <hip/hip_cooperative_groups.h>

namespace cg = cooperative_groups;

#define NN 100000
#define NE 1600000
#define EPSV 1e-5f
#define NBLK 256            // cooperative grid: 1 block per CU
#define NTILES 1563         // ceil(NN/64)
#define MAXT 7              // max tiles owned by one block (1563 = 6*256 + 27)

typedef float f32x4 __attribute__((ext_vector_type(4)));
typedef short s16x8 __attribute__((ext_vector_type(8)));

__device__ __forceinline__ unsigned short f2bf(float f) {
  unsigned int u = __float_as_uint(f);
  u += 0x7fffu + ((u >> 16) & 1u);   // round-to-nearest-even
  return (unsigned short)(u >> 16);
}

__device__ __forceinline__ float bf2f(unsigned short s) {
  return __uint_as_float(((unsigned int)s) << 16);
}

__device__ __forceinline__ ushort4 pack4(float4 v) {
  ushort4 s;
  s.x = f2bf(v.x); s.y = f2bf(v.y); s.z = f2bf(v.z); s.w = f2bf(v.w);
  return s;
}

// ---------------- bucket: eids[src][pos] = e (padded width 64) ----------------
__global__ __launch_bounds__(256) void k_bucket(
    const int* __restrict__ ei, int* __restrict__ cnt, int* __restrict__ eids) {
  int e = blockIdx.x * 256 + threadIdx.x;   // exactly NE threads
  int src = ei[e];
  int pos = atomicAdd(&cnt[src], 1);
  if (pos < 64) eids[(size_t)src * 64 + pos] = e;
}

// ---------------- gather: vmb[n] = bf16 mean of edge_attr rows of node n --------
// Persistent: 2048 blocks x 4 waves; each wave owns 13 consecutive nodes.
// Per node: 16 rows in flight (4 dwordx4 streams x 4 rows each).
__global__ __launch_bounds__(256) void k_gather(
    const int* __restrict__ cnt, const int* __restrict__ eids,
    const float4* __restrict__ ea4, ushort4* __restrict__ vmb4) {
  int wid = (blockIdx.x * 256 + threadIdx.x) >> 6;   // 0..8191
  int lane = threadIdx.x & 63;
  int grp = lane >> 4, q = lane & 15;
  int n0 = wid * 13;
  int nend = n0 + 13 < NN ? n0 + 13 : NN;
  for (int n = n0; n < nend; ++n) {
    const int* elist = eids + (size_t)n * 64;
    int c = cnt[n];
    int m = c < 64 ? c : 64;
    float ax = 0.f, ay = 0.f, az = 0.f, aw = 0.f;
    for (int e = 0; e < m; e += 16) {
      int rm = m - 1;
      int r0 = e + grp, r1 = e + 4 + grp, r2 = e + 8 + grp, r3 = e + 12 + grp;
      int i0 = elist[r0 < m ? r0 : rm];
      int i1 = elist[r1 < m ? r1 : rm];
      int i2 = elist[r2 < m ? r2 : rm];
      int i3 = elist[r3 < m ? r3 : rm];
      float4 v0 = ea4[(size_t)i0 * 16 + q];
      float4 v1 = ea4[(size_t)i1 * 16 + q];
      float4 v2 = ea4[(size_t)i2 * 16 + q];
      float4 v3 = ea4[(size_t)i3 * 16 + q];
      float m0 = r0 < m ? 1.f : 0.f, m1 = r1 < m ? 1.f : 0.f;
      float m2 = r2 < m ? 1.f : 0.f, m3 = r3 < m ? 1.f : 0.f;
      ax += m0 * v0.x + m1 * v1.x + m2 * v2.x + m3 * v3.x;
      ay += m0 * v0.y + m1 * v1.y + m2 * v2.y + m3 * v3.y;
      az += m0 * v0.z + m1 * v1.z + m2 * v2.z + m3 * v3.z;
      aw += m0 * v0.w + m1 * v1.w + m2 * v2.w + m3 * v3.w;
    }
    ax += __shfl_xor(ax, 16); ay += __shfl_xor(ay, 16);
    az += __shfl_xor(az, 16); aw += __shfl_xor(aw, 16);
    ax += __shfl_xor(ax, 32); ay += __shfl_xor(ay, 32);
    az += __shfl_xor(az, 32); aw += __shfl_xor(aw, 32);
    if (lane < 16) {
      float inv = 1.0f / fmaxf((float)c, 1.0f);
      float4 r; r.x = ax * inv; r.y = ay * inv; r.z = az * inv; r.w = aw * inv;
      vmb4[(size_t)n * 16 + lane] = pack4(r);
    }
  }
}

// ---------------- mega: g1 + BN-fold + gemm2 + BN-fold + gemm3 + BN3 ------------
struct MegaArgs {
  const float4* x4; const ushort4* vmb4; const float4* state4; const int* batch;
  const float4* w14; const float* b1;
  const float* W2; const float* b2; const float* g1; const float* be1;
  const float* W3; const float* b3; const float* g2; const float* be2;
  const float* g3; const float* be3;
  float* S1; float* Q1; float* S2; float* Q2; float* S3; float* Q3;
  float4* out4;
};

__global__ __launch_bounds__(256, 1) void k_mega(MegaArgs A) {
  __shared__ unsigned short ht[MAXT][64][72];   // resident h tiles (bf16)
  __shared__ unsigned short lc[64][200];        // g1 comb staging
  __shared__ unsigned short lw[64][200];        // W1 bf16; reused as folded-W [64][72]
  __shared__ float ssum[64], ssq[64];
  __shared__ float lA[64], lC[64], ld[64], red[256];
  cg::grid_group grid = cg::this_grid();
  const int tid = threadIdx.x;
  const int b = blockIdx.x;
  const int ntiles = (NTILES - b + NBLK - 1) / NBLK;   // 6 or 7
  const int lane = tid & 63, w = tid >> 6;
  const int rg = lane >> 4, ci = lane & 15;
  unsigned short (*lw2)[72] = (unsigned short(*)[72])lw;

  // ---- load W1 (bf16) ----
#pragma unroll
  for (int i = 0; i < 12; ++i) {
    int idx = tid + i * 256;
    int row = idx / 48, q = idx % 48;
    *(ushort4*)&lw[row][q * 4] = pack4(A.w14[idx]);
  }
  if (tid < 64) { ssum[tid] = 0.f; ssq[tid] = 0.f; }

  // ======== phase 1: GEMM1 + ReLU -> ht, stats S1/Q1 ========
  {
    float ls[4] = {0,0,0,0}, lq[4] = {0,0,0,0};
    for (int i = 0; i < ntiles; ++i) {
      int nodeBase = (b + i * NBLK) * 64;
#pragma unroll
      for (int it = 0; it < 4; ++it) {
        int idx = tid + it * 256;
        int node = idx >> 4, q = idx & 15;
        int g = nodeBase + node;
        float4 vx = {0,0,0,0}, vs = {0,0,0,0};
        ushort4 vm = {0,0,0,0};
        if (g < NN) {
          vx = A.x4[(size_t)g * 16 + q];
          vm = A.vmb4[(size_t)g * 16 + q];
          vs = A.state4[A.batch[g] * 16 + q];
        }
        *(ushort4*)&lc[node][q * 4]       = pack4(vx);
        *(ushort4*)&lc[node][64 + q * 4]  = vm;
        *(ushort4*)&lc[node][128 + q * 4] = pack4(vs);
      }
      __syncthreads();
      f32x4 acc[4] = {{0,0,0,0},{0,0,0,0},{0,0,0,0},{0,0,0,0}};
#pragma unroll
      for (int s = 0; s < 6; ++s) {
        int k0 = 32 * s + rg * 8;
        s16x8 a = *(const s16x8*)&lc[w * 16 + ci][k0];
#pragma unroll
        for (int c = 0; c < 4; ++c) {
          s16x8 bb = *(const s16x8*)&lw[c * 16 + ci][k0];
          acc[c] = __builtin_amdgcn_mfma_f32_16x16x32_bf16(a, bb, acc[c], 0, 0, 0);
        }
      }
#pragma unroll
      for (int c = 0; c < 4; ++c) {
        int col = c * 16 + ci;
        float bb = A.b1[col];
#pragma unroll
        for (int r = 0; r < 4; ++r) {
          int row = w * 16 + rg * 4 + r;
          float v = fmaxf(acc[c][r] + bb, 0.f);
          ht[i][row][col] = f2bf(v);
          if (nodeBase + row < NN) { ls[c] += v; lq[c] += v * v; }
        }
      }
      __syncthreads();   // protect lc before next tile's staging
    }
#pragma unroll
    for (int c = 0; c < 4; ++c) {
      atomicAdd(&ssum[c * 16 + ci], ls[c]);
      atomicAdd(&ssq[c * 16 + ci], lq[c]);
    }
    __syncthreads();
    if (tid < 64) {
      unsafeAtomicAdd(&A.S1[tid], ssum[tid]);
      unsafeAtomicAdd(&A.Q1[tid], ssq[tid]);
    }
    __threadfence();
  }
  grid.sync();

  // ======== phase 2: fold BN1 into W2, gemm2 + ReLU in place, stats S2/Q2 ========
  {
    if (tid < 64) {
      float Sv = atomicAdd(&A.S1[tid], 0.0f);   // coherent-point read
      float Qv = atomicAdd(&A.Q1[tid], 0.0f);
      float mu = Sv * (1.0f / NN);
      float var = Qv * (1.0f / NN) - mu * mu;
      float a = A.g1[tid] * rsqrtf(var + EPSV);
      lA[tid] = a; lC[tid] = A.be1[tid] - mu * a;
      ssum[tid] = 0.f; ssq[tid] = 0.f;
    }
    __syncthreads();
#pragma unroll
    for (int i = 0; i < 16; ++i) {
      int idx = tid + i * 256;
      lw2[idx >> 6][idx & 63] = f2bf(A.W2[idx] * lA[idx & 63]);
    }
    {
      int j = tid >> 2, p = tid & 3;
      const float* Wr = A.W2 + j * 64 + p * 16;
      float s = 0.f;
#pragma unroll
      for (int k = 0; k < 16; ++k) s += lC[p * 16 + k] * Wr[k];
      red[tid] = s;
    }
    __syncthreads();
    if (tid < 64) ld[tid] = A.b2[tid] + red[tid*4] + red[tid*4+1] + red[tid*4+2] + red[tid*4+3];
    __syncthreads();

    float ls[4] = {0,0,0,0}, lq[4] = {0,0,0,0};
    for (int i = 0; i < ntiles; ++i) {
      int nodeBase = (b + i * NBLK) * 64;
      f32x4 acc[4] = {{0,0,0,0},{0,0,0,0},{0,0,0,0},{0,0,0,0}};
#pragma unroll
      for (int s = 0; s < 2; ++s) {
        int k0 = 32 * s + rg * 8;
        s16x8 a = *(const s16x8*)&ht[i][w * 16 + ci][k0];
#pragma unroll
        for (int c = 0; c < 4; ++c) {
          s16x8 bb = *(const s16x8*)&lw2[c * 16 + ci][k0];
          acc[c] = __builtin_amdgcn_mfma_f32_16x16x32_bf16(a, bb, acc[c], 0, 0, 0);
        }
      }
#pragma unroll
      for (int c = 0; c < 4; ++c) {
        int col = c * 16 + ci;
        float dd = ld[col];
#pragma unroll
        for (int r = 0; r < 4; ++r) {
          int row = w * 16 + rg * 4 + r;
          float v = fmaxf(acc[c][r] + dd, 0.f);
          ht[i][row][col] = f2bf(v);   // in place: wave reads/writes only its rows
          if (nodeBase + row < NN) { ls[c] += v; lq[c] += v * v; }
        }
      }
    }
#pragma unroll
    for (int c = 0; c < 4; ++c) {
      atomicAdd(&ssum[c * 16 + ci], ls[c]);
      atomicAdd(&ssq[c * 16 + ci], lq[c]);
    }
    __syncthreads();
    if (tid < 64) {
      unsafeAtomicAdd(&A.S2[tid], ssum[tid]);
      unsafeAtomicAdd(&A.Q2[tid], ssq[tid]);
    }
    __threadfence();
  }
  grid.sync();

  // ======== phase 3: fold BN2 into W3, gemm3 in place, stats S3/Q3 ========
  {
    if (tid < 64) {
      float Sv = atomicAdd(&A.S2[tid], 0.0f);
      float Qv = atomicAdd(&A.Q2[tid], 0.0f);
      float mu = Sv * (1.0f / NN);
      float var = Qv * (1.0f / NN) - mu * mu;
      float a = A.g2[tid] * rsqrtf(var + EPSV);
      lA[tid] = a; lC[tid] = A.be2[tid] - mu * a;
      ssum[tid] = 0.f; ssq[tid] = 0.f;
    }
    __syncthreads();
#pragma unroll
    for (int i = 0; i < 16; ++i) {
      int idx = tid + i * 256;
      lw2[idx >> 6][idx & 63] = f2bf(A.W3[idx] * lA[idx & 63]);
    }
    {
      int j = tid >> 2, p = tid & 3;
      const float* Wr = A.W3 + j * 64 + p * 16;
      float s = 0.f;
#pragma unroll
      for (int k = 0; k < 16; ++k) s += lC[p * 16 + k] * Wr[k];
      red[tid] = s;
    }
    __syncthreads();
    if (tid < 64) ld[tid] = A.b3[tid] + red[tid*4] + red[tid*4+1] + red[tid*4+2] + red[tid*4+3];
    __syncthreads();

    float ls[4] = {0,0,0,0}, lq[4] = {0,0,0,0};
    for (int i = 0; i < ntiles; ++i) {
      int nodeBase = (b + i * NBLK) * 64;
      f32x4 acc[4] = {{0,0,0,0},{0,0,0,0},{0,0,0,0},{0,0,0,0}};
#pragma unroll
      for (int s = 0; s < 2; ++s) {
        int k0 = 32 * s + rg * 8;
        s16x8 a = *(const s16x8*)&ht[i][w * 16 + ci][k0];
#pragma unroll
        for (int c = 0; c < 4; ++c) {
          s16x8 bb = *(const s16x8*)&lw2[c * 16 + ci][k0];
          acc[c] = __builtin_amdgcn_mfma_f32_16x16x32_bf16(a, bb, acc[c], 0, 0, 0);
        }
      }
#pragma unroll
      for (int c = 0; c < 4; ++c) {
        int col = c * 16 + ci;
        float dd = ld[col];
#pragma unroll
        for (int r = 0; r < 4; ++r) {
          int row = w * 16 + rg * 4 + r;
          float v = acc[c][r] + dd;            // no ReLU
          ht[i][row][col] = f2bf(v);
          if (nodeBase + row < NN) { ls[c] += v; lq[c] += v * v; }
        }
      }
    }
#pragma unroll
    for (int c = 0; c < 4; ++c) {
      atomicAdd(&ssum[c * 16 + ci], ls[c]);
      atomicAdd(&ssq[c * 16 + ci], lq[c]);
    }
    __syncthreads();
    if (tid < 64) {
      unsafeAtomicAdd(&A.S3[tid], ssum[tid]);
      unsafeAtomicAdd(&A.Q3[tid], ssq[tid]);
    }
    __threadfence();
  }
  grid.sync();

  // ======== phase 4: BN3 normalize from LDS -> d_out (f32) ========
  {
    if (tid < 64) {
      float Sv = atomicAdd(&A.S3[tid], 0.0f);
      float Qv = atomicAdd(&A.Q3[tid], 0.0f);
      float mu = Sv * (1.0f / NN);
      float var = Qv * (1.0f / NN) - mu * mu;
      float a = A.g3[tid] * rsqrtf(var + EPSV);
      lA[tid] = a; lC[tid] = A.be3[tid] - mu * a;
    }
    __syncthreads();
    for (int i = 0; i < ntiles; ++i) {
      int nodeBase = (b + i * NBLK) * 64;
#pragma unroll
      for (int it = 0; it < 4; ++it) {
        int idx = tid + it * 256;
        int row = idx >> 4, q = idx & 15;
        int g = nodeBase + row;
        if (g < NN) {
          int k = q * 4;
          float4 o;
          o.x = bf2f(ht[i][row][k])     * lA[k]     + lC[k];
          o.y = bf2f(ht[i][row][k + 1]) * lA[k + 1] + lC[k + 1];
          o.z = bf2f(ht[i][row][k + 2]) * lA[k + 2] + lC[k + 2];
          o.w = bf2f(ht[i][row][k + 3]) * lA[k + 3] + lC[k + 3];
          A.out4[(size_t)g * 16 + q] = o;
        }
      }
    }
  }
}

extern "C" void kernel_launch(void* const* d_in, const int* in_sizes, int n_in,
                              void* d_out, int out_size, void* d_ws, size_t ws_size,
                              hipStream_t stream) {
  const float* x     = (const float*)d_in[0];
  const int*   ei    = (const int*)d_in[1];
  const float* ea    = (const float*)d_in[2];
  const float* state = (const float*)d_in[3];
  const int*   batch = (const int*)d_in[4];

  // Workspace:
  //   [0,       400000)  cnt
  //   [400000,  401536)  stats S1 Q1 S2 Q2 S3 Q3
  //   [401536, 26018432) eids (int, 64/node)
  //   [26018432,38818432) vmb (bf16 mean)
  char* ws = (char*)d_ws;
  int*   cnt  = (int*)ws;
  float* S1   = (float*)(ws + 400000);
  float* Q1 = S1 + 64;
  float* S2 = S1 + 128;
  float* Q2 = S1 + 192;
  float* S3 = S1 + 256;
  float* Q3 = S1 + 320;
  int*            eids = (int*)(ws + 401536);
  unsigned short* vmb  = (unsigned short*)(ws + 26018432);

  hipMemsetAsync(ws, 0, 401536, stream);   // cnt + stats

  k_bucket<<<NE / 256, 256, 0, stream>>>(ei, cnt, eids);
  k_gather<<<2048, 256, 0, stream>>>(cnt, eids, (const float4*)ea, (ushort4*)vmb);

  MegaArgs ma;
  ma.x4 = (const float4*)x; ma.vmb4 = (const ushort4*)vmb;
  ma.state4 = (const float4*)state; ma.batch = batch;
  ma.w14 = (const float4*)d_in[5]; ma.b1 = (const float*)d_in[6];
  ma.W2 = (const float*)d_in[9]; ma.b2 = (const float*)d_in[10];
  ma.g1 = (const float*)d_in[7]; ma.be1 = (const float*)d_in[8];
  ma.W3 = (const float*)d_in[13]; ma.b3 = (const float*)d_in[14];
  ma.g2 = (const float*)d_in[11]; ma.be2 = (const float*)d_in[12];
  ma.g3 = (const float*)d_in[15]; ma.be3 = (const float*)d_in[16];
  ma.S1 = S1; ma.Q1 = Q1; ma.S2 = S2; ma.Q2 = Q2; ma.S3 = S3; ma.Q3 = Q3;
  ma.out4 = (float4*)d_out;
  void* kargs[] = {&ma};
  hipLaunchCooperativeKernel((const void*)k_mega, dim3(NBLK), dim3(256), kargs, 0u, stream);
}

// Round 5
// 387.783 us; speedup vs baseline: 1.1569x; 1.1569x over previous
//
#include <hip/hip_runtime.h>

#define NN 100000
#define NE 1600000
#define EPSV 1e-5f

typedef float f32x4 __attribute__((ext_vector_type(4)));
typedef short s16x8 __attribute__((ext_vector_type(8)));

__device__ __forceinline__ unsigned short f2bf(float f) {
  unsigned int u = __float_as_uint(f);
  u += 0x7fffu + ((u >> 16) & 1u);   // round-to-nearest-even
  return (unsigned short)(u >> 16);
}

__device__ __forceinline__ float bf2f(unsigned short s) {
  return __uint_as_float(((unsigned int)s) << 16);
}

__device__ __forceinline__ ushort4 pack4(float4 v) {
  ushort4 s;
  s.x = f2bf(v.x); s.y = f2bf(v.y); s.z = f2bf(v.z); s.w = f2bf(v.w);
  return s;
}

// ---------------- bucket: eids[src][pos] = e (padded width 64) ----------------
__global__ __launch_bounds__(256) void k_bucket(
    const int* __restrict__ ei, int* __restrict__ cnt, int* __restrict__ eids) {
  int e = blockIdx.x * 256 + threadIdx.x;   // exactly NE threads
  int src = ei[e];
  int pos = atomicAdd(&cnt[src], 1);
  if (pos < 64) eids[(size_t)src * 64 + pos] = e;
}

// ---------------- gather: vmb[n] = bf16 mean of edge_attr rows of node n --------
// Persistent: 2048 blocks x 4 waves; each wave owns 13 consecutive nodes.
// 32 rows in flight per node (8 streams x 4 lane-groups), issued as 2 batches
// of 4 loads so peak live load-regs stays ~32 (VGPR<=64 -> 8 waves/SIMD).
__global__ __launch_bounds__(256) void k_gather(
    const int* __restrict__ cnt, const int* __restrict__ eids,
    const float4* __restrict__ ea4, ushort4* __restrict__ vmb4) {
  int wid = (blockIdx.x * 256 + threadIdx.x) >> 6;   // 0..8191
  int lane = threadIdx.x & 63;
  int grp = lane >> 4, q = lane & 15;
  int n0 = wid * 13;
  int nend = n0 + 13 < NN ? n0 + 13 : NN;
  for (int n = n0; n < nend; ++n) {
    const int* elist = eids + (size_t)n * 64;
    int c = cnt[n];
    int m = c < 64 ? c : 64;
    int rm = m - 1;
    float ax = 0.f, ay = 0.f, az = 0.f, aw = 0.f;
    {
      // single pass covers m <= 32 (99.98% of nodes)
      int r0 = grp,      r1 = 4 + grp,  r2 = 8 + grp,  r3 = 12 + grp;
      int r4 = 16 + grp, r5 = 20 + grp, r6 = 24 + grp, r7 = 28 + grp;
      int i0 = elist[r0 < m ? r0 : rm];
      int i1 = elist[r1 < m ? r1 : rm];
      int i2 = elist[r2 < m ? r2 : rm];
      int i3 = elist[r3 < m ? r3 : rm];
      int i4 = elist[r4 < m ? r4 : rm];
      int i5 = elist[r5 < m ? r5 : rm];
      int i6 = elist[r6 < m ? r6 : rm];
      int i7 = elist[r7 < m ? r7 : rm];
      // batch A issued
      float4 v0 = ea4[(size_t)i0 * 16 + q];
      float4 v1 = ea4[(size_t)i1 * 16 + q];
      float4 v2 = ea4[(size_t)i2 * 16 + q];
      float4 v3 = ea4[(size_t)i3 * 16 + q];
      // batch B issued before batch A is consumed
      float4 v4 = ea4[(size_t)i4 * 16 + q];
      float4 v5 = ea4[(size_t)i5 * 16 + q];
      float4 v6 = ea4[(size_t)i6 * 16 + q];
      float4 v7 = ea4[(size_t)i7 * 16 + q];
      float m0 = r0 < m ? 1.f : 0.f, m1 = r1 < m ? 1.f : 0.f;
      float m2 = r2 < m ? 1.f : 0.f, m3 = r3 < m ? 1.f : 0.f;
      // consume batch A (compiler waits vmcnt(4) here; B still in flight)
      ax += m0 * v0.x + m1 * v1.x + m2 * v2.x + m3 * v3.x;
      ay += m0 * v0.y + m1 * v1.y + m2 * v2.y + m3 * v3.y;
      az += m0 * v0.z + m1 * v1.z + m2 * v2.z + m3 * v3.z;
      aw += m0 * v0.w + m1 * v1.w + m2 * v2.w + m3 * v3.w;
      float m4 = r4 < m ? 1.f : 0.f, m5 = r5 < m ? 1.f : 0.f;
      float m6 = r6 < m ? 1.f : 0.f, m7 = r7 < m ? 1.f : 0.f;
      ax += m4 * v4.x + m5 * v5.x + m6 * v6.x + m7 * v7.x;
      ay += m4 * v4.y + m5 * v5.y + m6 * v6.y + m7 * v7.y;
      az += m4 * v4.z + m5 * v5.z + m6 * v6.z + m7 * v7.z;
      aw += m4 * v4.w + m5 * v5.w + m6 * v6.w + m7 * v7.w;
    }
    if (m > 32) {                       // rare (P ~ 2e-4)
      for (int e = 32; e < m; e += 16) {
        int r0 = e + grp, r1 = e + 4 + grp, r2 = e + 8 + grp, r3 = e + 12 + grp;
        int i0 = elist[r0 < m ? r0 : rm];
        int i1 = elist[r1 < m ? r1 : rm];
        int i2 = elist[r2 < m ? r2 : rm];
        int i3 = elist[r3 < m ? r3 : rm];
        float4 v0 = ea4[(size_t)i0 * 16 + q];
        float4 v1 = ea4[(size_t)i1 * 16 + q];
        float4 v2 = ea4[(size_t)i2 * 16 + q];
        float4 v3 = ea4[(size_t)i3 * 16 + q];
        float m0 = r0 < m ? 1.f : 0.f, m1 = r1 < m ? 1.f : 0.f;
        float m2 = r2 < m ? 1.f : 0.f, m3 = r3 < m ? 1.f : 0.f;
        ax += m0 * v0.x + m1 * v1.x + m2 * v2.x + m3 * v3.x;
        ay += m0 * v0.y + m1 * v1.y + m2 * v2.y + m3 * v3.y;
        az += m0 * v0.z + m1 * v1.z + m2 * v2.z + m3 * v3.z;
        aw += m0 * v0.w + m1 * v1.w + m2 * v2.w + m3 * v3.w;
      }
    }
    ax += __shfl_xor(ax, 16); ay += __shfl_xor(ay, 16);
    az += __shfl_xor(az, 16); aw += __shfl_xor(aw, 16);
    ax += __shfl_xor(ax, 32); ay += __shfl_xor(ay, 32);
    az += __shfl_xor(az, 32); aw += __shfl_xor(aw, 32);
    if (lane < 16) {
      float inv = 1.0f / fmaxf((float)c, 1.0f);
      float4 r; r.x = ax * inv; r.y = ay * inv; r.z = az * inv; r.w = aw * inv;
      vmb4[(size_t)n * 16 + lane] = pack4(r);
    }
  }
}

// ---------------- GEMM1: h1 = relu([x, v_mean, state[batch]] @ W1^T + b1), stats ----------------
__global__ __launch_bounds__(256) void k_g1(
    const float4* __restrict__ x4, const ushort4* __restrict__ vmb4,
    const float4* __restrict__ state4,
    const int* __restrict__ batch, const float4* __restrict__ w14,
    const float* __restrict__ b1, unsigned short* __restrict__ h1,
    float* __restrict__ Sout, float* __restrict__ Qout) {
  __shared__ unsigned short lc[64][200];   // comb tile, bf16, padded
  __shared__ unsigned short lw[64][200];   // W1 (64 out rows x 192 k), bf16; reused as out-tile
  __shared__ float ssum[64], ssq[64];
  const int tid = threadIdx.x;
  const int nodeBase = blockIdx.x * 64;
  if (tid < 64) { ssum[tid] = 0.f; ssq[tid] = 0.f; }
#pragma unroll
  for (int i = 0; i < 12; ++i) {           // W1: 3072 float4
    int idx = tid + i * 256;
    int row = idx / 48, q = idx % 48;
    *(ushort4*)&lw[row][q * 4] = pack4(w14[idx]);
  }
#pragma unroll
  for (int i = 0; i < 4; ++i) {            // comb: 64 nodes x 16 chunks
    int idx = tid + i * 256;
    int node = idx >> 4, q = idx & 15;
    int g = nodeBase + node;
    float4 vx = {0,0,0,0}, vs = {0,0,0,0};
    ushort4 vm = {0,0,0,0};
    if (g < NN) {
      vx = x4[(size_t)g * 16 + q];
      vm = vmb4[(size_t)g * 16 + q];
      int b = batch[g];
      vs = state4[b * 16 + q];
    }
    *(ushort4*)&lc[node][q * 4]       = pack4(vx);
    *(ushort4*)&lc[node][64 + q * 4]  = vm;
    *(ushort4*)&lc[node][128 + q * 4] = pack4(vs);
  }
  __syncthreads();
  const int lane = tid & 63, w = tid >> 6;
  const int rg = lane >> 4, ci = lane & 15;
  f32x4 acc[4] = {{0,0,0,0},{0,0,0,0},{0,0,0,0},{0,0,0,0}};
#pragma unroll
  for (int s = 0; s < 6; ++s) {
    int k0 = 32 * s + rg * 8;
    s16x8 a = *(const s16x8*)&lc[w * 16 + ci][k0];
#pragma unroll
    for (int c = 0; c < 4; ++c) {
      s16x8 b = *(const s16x8*)&lw[c * 16 + ci][k0];
      acc[c] = __builtin_amdgcn_mfma_f32_16x16x32_bf16(a, b, acc[c], 0, 0, 0);
    }
  }
  __syncthreads();                         // all MFMAs done; reuse lw as out-tile
  unsigned short (*lo)[72] = (unsigned short(*)[72])lw;
#pragma unroll
  for (int c = 0; c < 4; ++c) {
    int col = c * 16 + ci;
    float bb = b1[col];
    float ls = 0.f, lq = 0.f;
#pragma unroll
    for (int r = 0; r < 4; ++r) {
      int row = w * 16 + rg * 4 + r;
      float v = fmaxf(acc[c][r] + bb, 0.f);
      lo[row][col] = f2bf(v);
      if (nodeBase + row < NN) { ls += v; lq += v * v; }
    }
    atomicAdd(&ssum[col], ls);
    atomicAdd(&ssq[col], lq);
  }
  __syncthreads();
#pragma unroll
  for (int i = 0; i < 2; ++i) {            // coalesced 16B stores of the 64x64 tile
    int idx = tid + i * 256;
    int row = idx >> 3, q = idx & 7;
    int g = nodeBase + row;
    if (g < NN) *(s16x8*)&h1[(size_t)g * 64 + q * 8] = *(const s16x8*)&lo[row][q * 8];
  }
  if (tid < 64) {
    unsafeAtomicAdd(&Sout[tid], ssum[tid]);
    unsafeAtomicAdd(&Qout[tid], ssq[tid]);
  }
}

// ---------------- prep: fold BN(prev) into next-layer weights (one block) ----------------
__global__ __launch_bounds__(256) void k_prep(
    const float* __restrict__ Sin, const float* __restrict__ Qin,
    const float* __restrict__ gm, const float* __restrict__ bt,
    const float* __restrict__ W, const float* __restrict__ bias,
    unsigned short* __restrict__ wf, float* __restrict__ dout) {
  __shared__ float lA[64], lC[64], red[256];
  int t = threadIdx.x;
  if (t < 64) {
    float mu = Sin[t] * (1.0f / NN);
    float var = Qin[t] * (1.0f / NN) - mu * mu;
    float a = gm[t] * rsqrtf(var + EPSV);
    lA[t] = a;
    lC[t] = bt[t] - mu * a;
  }
  __syncthreads();
#pragma unroll
  for (int i = 0; i < 16; ++i) {           // fold 64x64 weights
    int idx = t + i * 256;
    wf[idx] = f2bf(W[idx] * lA[idx & 63]);
  }
  int j = t >> 2, p = t & 3;               // folded bias: d_j = b_j + sum_k c_k W[j][k]
  const float* Wr = W + j * 64 + p * 16;
  float s = 0.f;
#pragma unroll
  for (int k = 0; k < 16; ++k) s += lC[p * 16 + k] * Wr[k];
  red[t] = s;
  __syncthreads();
  if (t < 64) dout[t] = bias[t] + red[t * 4] + red[t * 4 + 1] + red[t * 4 + 2] + red[t * 4 + 3];
}

// ---------------- GEMM2/3: out = [relu](A @ Wf^T + d), stats ----------------
template <bool RELU>
__global__ __launch_bounds__(256) void k_gemm64(
    const s16x8* __restrict__ A8,     // bf16 [NN][64]
    const s16x8* __restrict__ w8,     // bf16 [64][64] folded
    const float* __restrict__ d,      // folded bias
    unsigned short* __restrict__ Obf,
    float* __restrict__ Sout, float* __restrict__ Qout) {
  __shared__ unsigned short la[64][72];    // A tile; reused as out-tile
  __shared__ unsigned short lwf[64][72];
  __shared__ float ssum[64], ssq[64];
  const int tid = threadIdx.x;
  const int nodeBase = blockIdx.x * 64;
  if (tid < 64) { ssum[tid] = 0.f; ssq[tid] = 0.f; }
#pragma unroll
  for (int i = 0; i < 2; ++i) {            // A tile: 512 x 16B
    int idx = tid + i * 256;
    int row = idx >> 3, q = idx & 7;
    int g = nodeBase + row;
    s16x8 v = {};
    if (g < NN) v = A8[(size_t)g * 8 + q];
    *(s16x8*)&la[row][q * 8] = v;
  }
#pragma unroll
  for (int i = 0; i < 2; ++i) {            // W tile (already folded bf16)
    int idx = tid + i * 256;
    int j = idx >> 3, q = idx & 7;
    *(s16x8*)&lwf[j][q * 8] = w8[idx];
  }
  __syncthreads();
  const int lane = tid & 63, w = tid >> 6;
  const int rg = lane >> 4, ci = lane & 15;
  f32x4 acc[4] = {{0,0,0,0},{0,0,0,0},{0,0,0,0},{0,0,0,0}};
#pragma unroll
  for (int s = 0; s < 2; ++s) {
    int k0 = 32 * s + rg * 8;
    s16x8 a = *(const s16x8*)&la[w * 16 + ci][k0];
#pragma unroll
    for (int c = 0; c < 4; ++c) {
      s16x8 b = *(const s16x8*)&lwf[c * 16 + ci][k0];
      acc[c] = __builtin_amdgcn_mfma_f32_16x16x32_bf16(a, b, acc[c], 0, 0, 0);
    }
  }
  __syncthreads();                         // reuse la as out-tile
  unsigned short (*lo)[72] = (unsigned short(*)[72])la;
#pragma unroll
  for (int c = 0; c < 4; ++c) {
    int col = c * 16 + ci;
    float dd = d[col];
    float ls = 0.f, lq = 0.f;
#pragma unroll
    for (int r = 0; r < 4; ++r) {
      int row = w * 16 + rg * 4 + r;
      float v = acc[c][r] + dd;
      if (RELU) v = fmaxf(v, 0.f);
      lo[row][col] = f2bf(v);
      if (nodeBase + row < NN) { ls += v; lq += v * v; }
    }
    atomicAdd(&ssum[col], ls);
    atomicAdd(&ssq[col], lq);
  }
  __syncthreads();
#pragma unroll
  for (int i = 0; i < 2; ++i) {
    int idx = tid + i * 256;
    int row = idx >> 3, q = idx & 7;
    int g = nodeBase + row;
    if (g < NN) *(s16x8*)&Obf[(size_t)g * 64 + q * 8] = *(const s16x8*)&lo[row][q * 8];
  }
  if (tid < 64) {
    unsafeAtomicAdd(&Sout[tid], ssum[tid]);
    unsafeAtomicAdd(&Qout[tid], ssq[tid]);
  }
}

// ---------------- final BN3 elementwise (bf16 in, f32 out) ----------------
__global__ __launch_bounds__(256) void k_bn3(
    const s16x8* __restrict__ h3b, const float* __restrict__ gm,
    const float* __restrict__ bt, const float* __restrict__ S,
    const float* __restrict__ Q, float4* __restrict__ out) {
  __shared__ float lA[64], lC[64];
  const int tid = threadIdx.x;
  if (tid < 64) {
    float mu = S[tid] * (1.0f / NN);
    float var = Q[tid] * (1.0f / NN) - mu * mu;
    float a = gm[tid] * rsqrtf(var + EPSV);
    lA[tid] = a;
    lC[tid] = bt[tid] - mu * a;
  }
  __syncthreads();
  const int total = NN * 8;                // short8 units
  for (int idx = blockIdx.x * 256 + tid; idx < total; idx += gridDim.x * 256) {
    s16x8 v = h3b[idx];
    int k = (idx & 7) * 8;
    float4 o0, o1;
    o0.x = bf2f((unsigned short)v[0]) * lA[k]     + lC[k];
    o0.y = bf2f((unsigned short)v[1]) * lA[k + 1] + lC[k + 1];
    o0.z = bf2f((unsigned short)v[2]) * lA[k + 2] + lC[k + 2];
    o0.w = bf2f((unsigned short)v[3]) * lA[k + 3] + lC[k + 3];
    o1.x = bf2f((unsigned short)v[4]) * lA[k + 4] + lC[k + 4];
    o1.y = bf2f((unsigned short)v[5]) * lA[k + 5] + lC[k + 5];
    o1.z = bf2f((unsigned short)v[6]) * lA[k + 6] + lC[k + 6];
    o1.w = bf2f((unsigned short)v[7]) * lA[k + 7] + lC[k + 7];
    out[idx * 2]     = o0;
    out[idx * 2 + 1] = o1;
  }
}

extern "C" void kernel_launch(void* const* d_in, const int* in_sizes, int n_in,
                              void* d_out, int out_size, void* d_ws, size_t ws_size,
                              hipStream_t stream) {
  const float* x     = (const float*)d_in[0];
  const int*   ei    = (const int*)d_in[1];
  const float* ea    = (const float*)d_in[2];
  const float* state = (const float*)d_in[3];
  const int*   batch = (const int*)d_in[4];
  const float* W1  = (const float*)d_in[5];
  const float* b1  = (const float*)d_in[6];
  const float* g1  = (const float*)d_in[7];
  const float* be1 = (const float*)d_in[8];
  const float* W2  = (const float*)d_in[9];
  const float* b2  = (const float*)d_in[10];
  const float* g2  = (const float*)d_in[11];
  const float* be2 = (const float*)d_in[12];
  const float* W3  = (const float*)d_in[13];
  const float* b3  = (const float*)d_in[14];
  const float* g3  = (const float*)d_in[15];
  const float* be3 = (const float*)d_in[16];

  // Workspace layout:
  //   [0,       400000)  cnt
  //   [400000,  401536)  stats S1 Q1 S2 Q2 S3 Q3
  //   [401536,  409728)  w2f bf16       [409728, 409984) d2
  //   [409984,  418176)  w3f bf16       [418176, 418432) d3
  //   [418432, 26018432) eids (int, 64/node)   == h3 bf16 alias (12.8 MB)
  //   [26018432,38818432) vmb bf16 mean        == h2 bf16 alias
  //   [38818432,51618432) h1 bf16
  char* ws = (char*)d_ws;
  int*   cnt  = (int*)ws;
  float* S1   = (float*)(ws + 400000);
  float* Q1 = S1 + 64;
  float* S2 = S1 + 128;
  float* Q2 = S1 + 192;
  float* S3 = S1 + 256;
  float* Q3 = S1 + 320;
  unsigned short* w2f = (unsigned short*)(ws + 401536);
  float*          d2  = (float*)(ws + 409728);
  unsigned short* w3f = (unsigned short*)(ws + 409984);
  float*          d3  = (float*)(ws + 418176);
  int*            eids = (int*)(ws + 418432);
  unsigned short* h3b  = (unsigned short*)(ws + 418432);   // alias eids
  unsigned short* vmb  = (unsigned short*)(ws + 26018432);
  unsigned short* h2   = (unsigned short*)(ws + 26018432); // alias vmb
  unsigned short* h1   = (unsigned short*)(ws + 38818432);

  hipMemsetAsync(ws, 0, 401536, stream);   // cnt + stats

  k_bucket<<<NE / 256, 256, 0, stream>>>(ei, cnt, eids);
  k_gather<<<2048, 256, 0, stream>>>(cnt, eids, (const float4*)ea, (ushort4*)vmb);

  const int nblk = (NN + 63) / 64;   // 1563
  k_g1<<<nblk, 256, 0, stream>>>((const float4*)x, (const ushort4*)vmb,
                                 (const float4*)state, batch, (const float4*)W1,
                                 b1, h1, S1, Q1);
  k_prep<<<1, 256, 0, stream>>>(S1, Q1, g1, be1, W2, b2, w2f, d2);
  k_gemm64<true><<<nblk, 256, 0, stream>>>(
      (const s16x8*)h1, (const s16x8*)w2f, d2, h2, S2, Q2);
  k_prep<<<1, 256, 0, stream>>>(S2, Q2, g2, be2, W3, b3, w3f, d3);
  k_gemm64<false><<<nblk, 256, 0, stream>>>(
      (const s16x8*)h2, (const s16x8*)w3f, d3, h3b, S3, Q3);
  k_bn3<<<2048, 256, 0, stream>>>((const s16x8*)h3b, g3, be3, S3, Q3, (float4*)d_out);
}

// Round 6
// 363.760 us; speedup vs baseline: 1.2333x; 1.0660x over previous
//
#include <hip/hip_runtime.h>

#define NN 100000
#define NE 1600000
#define EPSV 1e-5f
#define NTILE 1563          // ceil(NN/64)

typedef float f32x4 __attribute__((ext_vector_type(4)));
typedef short s16x8 __attribute__((ext_vector_type(8)));

__device__ __forceinline__ unsigned short f2bf(float f) {
  unsigned int u = __float_as_uint(f);
  u += 0x7fffu + ((u >> 16) & 1u);   // round-to-nearest-even
  return (unsigned short)(u >> 16);
}

__device__ __forceinline__ float bf2f(unsigned short s) {
  return __uint_as_float(((unsigned int)s) << 16);
}

__device__ __forceinline__ ushort4 pack4(float4 v) {
  ushort4 s;
  s.x = f2bf(v.x); s.y = f2bf(v.y); s.z = f2bf(v.z); s.w = f2bf(v.w);
  return s;
}

// ---------------- K1: bucket (4/5 of blocks) ∥ g1a partial GEMM (1/5) ----------
// bucket: eids[src][pos] = e (padded width 64), cnt histogram via atomics.
// g1a: ph = [x, state[batch]] @ W1(x,state-cols)^T, f32, stored in the exact
//      per-thread register layout g1b will reload (no transpose, 16B/lane).
__global__ __launch_bounds__(256) void k_bucket_g1a(
    const int* __restrict__ ei, int* __restrict__ cnt, int* __restrict__ eids,
    const float4* __restrict__ x4, const float4* __restrict__ state4,
    const int* __restrict__ batch, const float4* __restrict__ w14,
    f32x4* __restrict__ ph) {
  __shared__ unsigned short lx[64][136];   // x(0..63) + state(64..127) per node
  __shared__ unsigned short lw[64][136];   // W1 x-cols + state-cols per out-row
  const int idx = blockIdx.x;
  const int tid = threadIdx.x;
  const bool is_g1a = ((idx % 5) == 2) && (idx / 5 < NTILE);
  if (!is_g1a) {
    int nga = idx / 5 + (((idx % 5) > 2) ? 1 : 0);   // g1a blocks before idx
    if (nga > NTILE) nga = NTILE;
    int e = (idx - nga) * 256 + tid;                 // bucket_id * 256 + tid
    int src = ei[e];
    int pos = atomicAdd(&cnt[src], 1);
    if (pos < 64) eids[(size_t)src * 64 + pos] = e;
    return;
  }
  const int tile = idx / 5;
  const int nodeBase = tile * 64;
#pragma unroll
  for (int i = 0; i < 4; ++i) {            // W1: x-part q0..15, state-part q32..47
    int t = tid + i * 256;                 // 0..1023
    int j = t >> 4, q = t & 15;
    *(ushort4*)&lw[j][q * 4]      = pack4(w14[j * 48 + q]);
    *(ushort4*)&lw[j][64 + q * 4] = pack4(w14[j * 48 + 32 + q]);
  }
#pragma unroll
  for (int i = 0; i < 4; ++i) {            // node tile: x + state[batch]
    int t = tid + i * 256;
    int node = t >> 4, q = t & 15;
    int g = nodeBase + node;
    float4 vx = {0,0,0,0}, vs = {0,0,0,0};
    if (g < NN) {
      vx = x4[(size_t)g * 16 + q];
      vs = state4[batch[g] * 16 + q];
    }
    *(ushort4*)&lx[node][q * 4]      = pack4(vx);
    *(ushort4*)&lx[node][64 + q * 4] = pack4(vs);
  }
  __syncthreads();
  const int lane = tid & 63, w = tid >> 6;
  const int rg = lane >> 4, ci = lane & 15;
  f32x4 acc[4] = {{0,0,0,0},{0,0,0,0},{0,0,0,0},{0,0,0,0}};
#pragma unroll
  for (int s = 0; s < 4; ++s) {            // 128 packed k-cols
    int k0 = 32 * s + rg * 8;
    s16x8 a = *(const s16x8*)&lx[w * 16 + ci][k0];
#pragma unroll
    for (int c = 0; c < 4; ++c) {
      s16x8 b = *(const s16x8*)&lw[c * 16 + ci][k0];
      acc[c] = __builtin_amdgcn_mfma_f32_16x16x32_bf16(a, b, acc[c], 0, 0, 0);
    }
  }
#pragma unroll
  for (int c = 0; c < 4; ++c)              // coalesced 16B/lane, layout-matched
    ph[(size_t)tile * 1024 + tid * 4 + c] = acc[c];
}

// ---------------- gather: vmb[n] = bf16 mean of edge_attr rows of node n --------
// (byte-identical to round-5 version: persistent, 32 rows in flight)
__global__ __launch_bounds__(256) void k_gather(
    const int* __restrict__ cnt, const int* __restrict__ eids,
    const float4* __restrict__ ea4, ushort4* __restrict__ vmb4) {
  int wid = (blockIdx.x * 256 + threadIdx.x) >> 6;   // 0..8191
  int lane = threadIdx.x & 63;
  int grp = lane >> 4, q = lane & 15;
  int n0 = wid * 13;
  int nend = n0 + 13 < NN ? n0 + 13 : NN;
  for (int n = n0; n < nend; ++n) {
    const int* elist = eids + (size_t)n * 64;
    int c = cnt[n];
    int m = c < 64 ? c : 64;
    int rm = m - 1;
    float ax = 0.f, ay = 0.f, az = 0.f, aw = 0.f;
    {
      int r0 = grp,      r1 = 4 + grp,  r2 = 8 + grp,  r3 = 12 + grp;
      int r4 = 16 + grp, r5 = 20 + grp, r6 = 24 + grp, r7 = 28 + grp;
      int i0 = elist[r0 < m ? r0 : rm];
      int i1 = elist[r1 < m ? r1 : rm];
      int i2 = elist[r2 < m ? r2 : rm];
      int i3 = elist[r3 < m ? r3 : rm];
      int i4 = elist[r4 < m ? r4 : rm];
      int i5 = elist[r5 < m ? r5 : rm];
      int i6 = elist[r6 < m ? r6 : rm];
      int i7 = elist[r7 < m ? r7 : rm];
      float4 v0 = ea4[(size_t)i0 * 16 + q];
      float4 v1 = ea4[(size_t)i1 * 16 + q];
      float4 v2 = ea4[(size_t)i2 * 16 + q];
      float4 v3 = ea4[(size_t)i3 * 16 + q];
      float4 v4 = ea4[(size_t)i4 * 16 + q];
      float4 v5 = ea4[(size_t)i5 * 16 + q];
      float4 v6 = ea4[(size_t)i6 * 16 + q];
      float4 v7 = ea4[(size_t)i7 * 16 + q];
      float m0 = r0 < m ? 1.f : 0.f, m1 = r1 < m ? 1.f : 0.f;
      float m2 = r2 < m ? 1.f : 0.f, m3 = r3 < m ? 1.f : 0.f;
      ax += m0 * v0.x + m1 * v1.x + m2 * v2.x + m3 * v3.x;
      ay += m0 * v0.y + m1 * v1.y + m2 * v2.y + m3 * v3.y;
      az += m0 * v0.z + m1 * v1.z + m2 * v2.z + m3 * v3.z;
      aw += m0 * v0.w + m1 * v1.w + m2 * v2.w + m3 * v3.w;
      float m4 = r4 < m ? 1.f : 0.f, m5 = r5 < m ? 1.f : 0.f;
      float m6 = r6 < m ? 1.f : 0.f, m7 = r7 < m ? 1.f : 0.f;
      ax += m4 * v4.x + m5 * v5.x + m6 * v6.x + m7 * v7.x;
      ay += m4 * v4.y + m5 * v5.y + m6 * v6.y + m7 * v7.y;
      az += m4 * v4.z + m5 * v5.z + m6 * v6.z + m7 * v7.z;
      aw += m4 * v4.w + m5 * v5.w + m6 * v6.w + m7 * v7.w;
    }
    if (m > 32) {
      for (int e = 32; e < m; e += 16) {
        int r0 = e + grp, r1 = e + 4 + grp, r2 = e + 8 + grp, r3 = e + 12 + grp;
        int i0 = elist[r0 < m ? r0 : rm];
        int i1 = elist[r1 < m ? r1 : rm];
        int i2 = elist[r2 < m ? r2 : rm];
        int i3 = elist[r3 < m ? r3 : rm];
        float4 v0 = ea4[(size_t)i0 * 16 + q];
        float4 v1 = ea4[(size_t)i1 * 16 + q];
        float4 v2 = ea4[(size_t)i2 * 16 + q];
        float4 v3 = ea4[(size_t)i3 * 16 + q];
        float m0 = r0 < m ? 1.f : 0.f, m1 = r1 < m ? 1.f : 0.f;
        float m2 = r2 < m ? 1.f : 0.f, m3 = r3 < m ? 1.f : 0.f;
        ax += m0 * v0.x + m1 * v1.x + m2 * v2.x + m3 * v3.x;
        ay += m0 * v0.y + m1 * v1.y + m2 * v2.y + m3 * v3.y;
        az += m0 * v0.z + m1 * v1.z + m2 * v2.z + m3 * v3.z;
        aw += m0 * v0.w + m1 * v1.w + m2 * v2.w + m3 * v3.w;
      }
    }
    ax += __shfl_xor(ax, 16); ay += __shfl_xor(ay, 16);
    az += __shfl_xor(az, 16); aw += __shfl_xor(aw, 16);
    ax += __shfl_xor(ax, 32); ay += __shfl_xor(ay, 32);
    az += __shfl_xor(az, 32); aw += __shfl_xor(aw, 32);
    if (lane < 16) {
      float inv = 1.0f / fmaxf((float)c, 1.0f);
      float4 r; r.x = ax * inv; r.y = ay * inv; r.z = az * inv; r.w = aw * inv;
      vmb4[(size_t)n * 16 + lane] = pack4(r);
    }
  }
}

// ---------------- g1b: h1 = relu(ph + vmean @ W1v^T + b1), stats S1/Q1 ----------
__global__ __launch_bounds__(256) void k_g1b(
    const ushort4* __restrict__ vmb4, const float4* __restrict__ w14,
    const float* __restrict__ b1, const f32x4* __restrict__ ph,
    unsigned short* __restrict__ h1,
    float* __restrict__ Sout, float* __restrict__ Qout) {
  __shared__ unsigned short lv[64][72];    // vmean tile
  __shared__ unsigned short lwv[64][72];   // W1 vm-cols; reused as out-tile
  __shared__ float ssum[64], ssq[64];
  const int tid = threadIdx.x;
  const int tile = blockIdx.x;
  const int nodeBase = tile * 64;
  if (tid < 64) { ssum[tid] = 0.f; ssq[tid] = 0.f; }
#pragma unroll
  for (int i = 0; i < 4; ++i) {
    int t = tid + i * 256;
    int j = t >> 4, q = t & 15;
    *(ushort4*)&lwv[j][q * 4] = pack4(w14[j * 48 + 16 + q]);   // cols 64..127
    int g = nodeBase + j;
    ushort4 vm = {0,0,0,0};
    if (g < NN) vm = vmb4[(size_t)g * 16 + q];
    *(ushort4*)&lv[j][q * 4] = vm;
  }
  __syncthreads();
  const int lane = tid & 63, w = tid >> 6;
  const int rg = lane >> 4, ci = lane & 15;
  f32x4 acc[4];
#pragma unroll
  for (int c = 0; c < 4; ++c) acc[c] = ph[(size_t)tile * 1024 + tid * 4 + c];
#pragma unroll
  for (int s = 0; s < 2; ++s) {
    int k0 = 32 * s + rg * 8;
    s16x8 a = *(const s16x8*)&lv[w * 16 + ci][k0];
#pragma unroll
    for (int c = 0; c < 4; ++c) {
      s16x8 b = *(const s16x8*)&lwv[c * 16 + ci][k0];
      acc[c] = __builtin_amdgcn_mfma_f32_16x16x32_bf16(a, b, acc[c], 0, 0, 0);
    }
  }
  __syncthreads();                         // lwv reads done; reuse as out-tile
  unsigned short (*lo)[72] = (unsigned short(*)[72])lwv;
#pragma unroll
  for (int c = 0; c < 4; ++c) {
    int col = c * 16 + ci;
    float bb = b1[col];
    float ls = 0.f, lq = 0.f;
#pragma unroll
    for (int r = 0; r < 4; ++r) {
      int row = w * 16 + rg * 4 + r;
      float v = fmaxf(acc[c][r] + bb, 0.f);
      lo[row][col] = f2bf(v);
      if (nodeBase + row < NN) { ls += v; lq += v * v; }
    }
    atomicAdd(&ssum[col], ls);
    atomicAdd(&ssq[col], lq);
  }
  __syncthreads();
#pragma unroll
  for (int i = 0; i < 2; ++i) {            // coalesced 16B stores
    int t = tid + i * 256;
    int row = t >> 3, q = t & 7;
    int g = nodeBase + row;
    if (g < NN) *(s16x8*)&h1[(size_t)g * 64 + q * 8] = *(const s16x8*)&lo[row][q * 8];
  }
  if (tid < 64) {
    unsafeAtomicAdd(&Sout[tid], ssum[tid]);
    unsafeAtomicAdd(&Qout[tid], ssq[tid]);
  }
}

// ---------------- GEMM2/3 with in-kernel BN fold: out = [relu](A @ Wf^T + d) ----
template <bool RELU>
__global__ __launch_bounds__(256) void k_gemm64f(
    const s16x8* __restrict__ A8,     // bf16 [NN][64]
    const float* __restrict__ Wf,     // f32 [64][64] raw weights
    const float* __restrict__ bias,
    const float* __restrict__ gm, const float* __restrict__ bt,
    const float* __restrict__ Sin, const float* __restrict__ Qin,
    unsigned short* __restrict__ Obf,
    float* __restrict__ Sout, float* __restrict__ Qout) {
  __shared__ unsigned short la[64][72];    // A tile; reused as out-tile
  __shared__ unsigned short lwf[64][72];   // folded W bf16
  __shared__ float lA[64], lC[64], ld[64], red[256], ssum[64], ssq[64];
  const int tid = threadIdx.x;
  const int nodeBase = blockIdx.x * 64;
  if (tid < 64) {
    float mu = Sin[tid] * (1.0f / NN);
    float var = Qin[tid] * (1.0f / NN) - mu * mu;
    float a = gm[tid] * rsqrtf(var + EPSV);
    lA[tid] = a; lC[tid] = bt[tid] - mu * a;
    ssum[tid] = 0.f; ssq[tid] = 0.f;
  }
  __syncthreads();
#pragma unroll
  for (int i = 0; i < 2; ++i) {            // A tile: 512 x 16B
    int t = tid + i * 256;
    int row = t >> 3, q = t & 7;
    int g = nodeBase + row;
    s16x8 v = {};
    if (g < NN) v = A8[(size_t)g * 8 + q];
    *(s16x8*)&la[row][q * 8] = v;
  }
#pragma unroll
  for (int i = 0; i < 16; ++i) {           // fold weights by BN scale a_k
    int t = tid + i * 256;
    lwf[t >> 6][t & 63] = f2bf(Wf[t] * lA[t & 63]);
  }
  {                                        // folded bias partials
    int j = tid >> 2, p = tid & 3;
    const float* Wr = Wf + j * 64 + p * 16;
    float s = 0.f;
#pragma unroll
    for (int k = 0; k < 16; ++k) s += lC[p * 16 + k] * Wr[k];
    red[tid] = s;
  }
  __syncthreads();
  if (tid < 64) ld[tid] = bias[tid] + red[tid*4] + red[tid*4+1] + red[tid*4+2] + red[tid*4+3];
  __syncthreads();
  const int lane = tid & 63, w = tid >> 6;
  const int rg = lane >> 4, ci = lane & 15;
  f32x4 acc[4] = {{0,0,0,0},{0,0,0,0},{0,0,0,0},{0,0,0,0}};
#pragma unroll
  for (int s = 0; s < 2; ++s) {
    int k0 = 32 * s + rg * 8;
    s16x8 a = *(const s16x8*)&la[w * 16 + ci][k0];
#pragma unroll
    for (int c = 0; c < 4; ++c) {
      s16x8 b = *(const s16x8*)&lwf[c * 16 + ci][k0];
      acc[c] = __builtin_amdgcn_mfma_f32_16x16x32_bf16(a, b, acc[c], 0, 0, 0);
    }
  }
  __syncthreads();                         // reuse la as out-tile
  unsigned short (*lo)[72] = (unsigned short(*)[72])la;
#pragma unroll
  for (int c = 0; c < 4; ++c) {
    int col = c * 16 + ci;
    float dd = ld[col];
    float ls = 0.f, lq = 0.f;
#pragma unroll
    for (int r = 0; r < 4; ++r) {
      int row = w * 16 + rg * 4 + r;
      float v = acc[c][r] + dd;
      if (RELU) v = fmaxf(v, 0.f);
      lo[row][col] = f2bf(v);
      if (nodeBase + row < NN) { ls += v; lq += v * v; }
    }
    atomicAdd(&ssum[col], ls);
    atomicAdd(&ssq[col], lq);
  }
  __syncthreads();
#pragma unroll
  for (int i = 0; i < 2; ++i) {
    int t = tid + i * 256;
    int row = t >> 3, q = t & 7;
    int g = nodeBase + row;
    if (g < NN) *(s16x8*)&Obf[(size_t)g * 64 + q * 8] = *(const s16x8*)&lo[row][q * 8];
  }
  if (tid < 64) {
    unsafeAtomicAdd(&Sout[tid], ssum[tid]);
    unsafeAtomicAdd(&Qout[tid], ssq[tid]);
  }
}

// ---------------- final BN3 elementwise (bf16 in, f32 out) ----------------
__global__ __launch_bounds__(256) void k_bn3(
    const s16x8* __restrict__ h3b, const float* __restrict__ gm,
    const float* __restrict__ bt, const float* __restrict__ S,
    const float* __restrict__ Q, float4* __restrict__ out) {
  __shared__ float lA[64], lC[64];
  const int tid = threadIdx.x;
  if (tid < 64) {
    float mu = S[tid] * (1.0f / NN);
    float var = Q[tid] * (1.0f / NN) - mu * mu;
    float a = gm[tid] * rsqrtf(var + EPSV);
    lA[tid] = a;
    lC[tid] = bt[tid] - mu * a;
  }
  __syncthreads();
  const int total = NN * 8;                // short8 units
  for (int idx = blockIdx.x * 256 + tid; idx < total; idx += gridDim.x * 256) {
    s16x8 v = h3b[idx];
    int k = (idx & 7) * 8;
    float4 o0, o1;
    o0.x = bf2f((unsigned short)v[0]) * lA[k]     + lC[k];
    o0.y = bf2f((unsigned short)v[1]) * lA[k + 1] + lC[k + 1];
    o0.z = bf2f((unsigned short)v[2]) * lA[k + 2] + lC[k + 2];
    o0.w = bf2f((unsigned short)v[3]) * lA[k + 3] + lC[k + 3];
    o1.x = bf2f((unsigned short)v[4]) * lA[k + 4] + lC[k + 4];
    o1.y = bf2f((unsigned short)v[5]) * lA[k + 5] + lC[k + 5];
    o1.z = bf2f((unsigned short)v[6]) * lA[k + 6] + lC[k + 6];
    o1.w = bf2f((unsigned short)v[7]) * lA[k + 7] + lC[k + 7];
    out[idx * 2]     = o0;
    out[idx * 2 + 1] = o1;
  }
}

extern "C" void kernel_launch(void* const* d_in, const int* in_sizes, int n_in,
                              void* d_out, int out_size, void* d_ws, size_t ws_size,
                              hipStream_t stream) {
  const float* x     = (const float*)d_in[0];
  const int*   ei    = (const int*)d_in[1];
  const float* ea    = (const float*)d_in[2];
  const float* state = (const float*)d_in[3];
  const int*   batch = (const int*)d_in[4];
  const float* W1  = (const float*)d_in[5];
  const float* b1  = (const float*)d_in[6];
  const float* g1  = (const float*)d_in[7];
  const float* be1 = (const float*)d_in[8];
  const float* W2  = (const float*)d_in[9];
  const float* b2  = (const float*)d_in[10];
  const float* g2  = (const float*)d_in[11];
  const float* be2 = (const float*)d_in[12];
  const float* W3  = (const float*)d_in[13];
  const float* b3  = (const float*)d_in[14];
  const float* g3  = (const float*)d_in[15];
  const float* be3 = (const float*)d_in[16];

  // Workspace layout:
  //   [0,       400000)   cnt
  //   [400000,  401536)   stats S1 Q1 S2 Q2 S3 Q3
  //   [401536, 26018432)  eids (int, 64/node)   == h3 bf16 alias (12.8 MB)
  //   [26018432,38818432) vmb bf16 mean         == h2 bf16 alias
  //   [38818432,51618432) h1 bf16
  //   [51618432,77218432) ph f32 partial (g1a -> g1b)
  char* ws = (char*)d_ws;
  int*   cnt  = (int*)ws;
  float* S1   = (float*)(ws + 400000);
  float* Q1 = S1 + 64;
  float* S2 = S1 + 128;
  float* Q2 = S1 + 192;
  float* S3 = S1 + 256;
  float* Q3 = S1 + 320;
  int*            eids = (int*)(ws + 401536);
  unsigned short* h3b  = (unsigned short*)(ws + 401536);   // alias eids
  unsigned short* vmb  = (unsigned short*)(ws + 26018432);
  unsigned short* h2   = (unsigned short*)(ws + 26018432); // alias vmb
  unsigned short* h1   = (unsigned short*)(ws + 38818432);
  f32x4*          ph   = (f32x4*)(ws + 51618432);

  hipMemsetAsync(ws, 0, 401536, stream);   // cnt + stats

  k_bucket_g1a<<<6250 + NTILE, 256, 0, stream>>>(
      ei, cnt, eids, (const float4*)x, (const float4*)state, batch,
      (const float4*)W1, ph);
  k_gather<<<2048, 256, 0, stream>>>(cnt, eids, (const float4*)ea, (ushort4*)vmb);
  k_g1b<<<NTILE, 256, 0, stream>>>((const ushort4*)vmb, (const float4*)W1,
                                   b1, ph, h1, S1, Q1);
  k_gemm64f<true><<<NTILE, 256, 0, stream>>>(
      (const s16x8*)h1, W2, b2, g1, be1, S1, Q1, h2, S2, Q2);
  k_gemm64f<false><<<NTILE, 256, 0, stream>>>(
      (const s16x8*)h2, W3, b3, g2, be2, S2, Q2, h3b, S3, Q3);
  k_bn3<<<2048, 256, 0, stream>>>((const s16x8*)h3b, g3, be3, S3, Q3, (float4*)d_out);
}